// Round 17
// baseline (265.385 us; speedup 1.0000x reference)
//
#include <hip/hip_runtime.h>

typedef __bf16 bf16x8 __attribute__((ext_vector_type(8)));
typedef __bf16 bf16x4 __attribute__((ext_vector_type(4)));
typedef float  f32x16 __attribute__((ext_vector_type(16)));

#define DDEC  176
#define DSP   54
#define HID   256
#define RPW   32             // rows per wave (32x32 MFMA N-dim)
#define WPB   8              // waves per block
#define BM    (RPW * WPB)    // 256 rows per block
#define NTHR  (WPB * 64)     // 512 threads
#define CSZ   8192           // elems per 32-col weight chunk (16KB)
#define W1_OFF 65536
#define W2_OFF 131072
#define MLP_WS 139264

struct Biases { const float* b1[3]; const float* b2[3]; };

// ---- prep: pad/transpose weights to bf16 [col][256 k] per layer
// W0p[256][256] (k<222 = w0[k][n], k==222 = b0[n], else 0), W1p[256][256], W2p[32][256]
__global__ __launch_bounds__(256) void prep_weights(
    const float* __restrict__ w0a, const float* __restrict__ w1a, const float* __restrict__ w2a,
    const float* __restrict__ w0b, const float* __restrict__ w1b, const float* __restrict__ w2b,
    const float* __restrict__ w0c, const float* __restrict__ w1c, const float* __restrict__ w2c,
    const float* __restrict__ b0a, const float* __restrict__ b0b, const float* __restrict__ b0c,
    __bf16* __restrict__ ws)
{
  int idx = blockIdx.x * 256 + threadIdx.x;
  if (idx >= 3 * MLP_WS) return;
  int m = idx / MLP_WS;
  int r = idx - m * MLP_WS;
  const float* w0 = (m == 0) ? w0a : (m == 1) ? w0b : w0c;
  const float* w1 = (m == 0) ? w1a : (m == 1) ? w1b : w1c;
  const float* w2 = (m == 0) ? w2a : (m == 1) ? w2b : w2c;
  const float* b0 = (m == 0) ? b0a : (m == 1) ? b0b : b0c;
  float v;
  if (r < W1_OFF) {
    int n = r >> 8, k = r & 255;
    v = (k < 222) ? w0[k * HID + n] : (k == 222 ? b0[n] : 0.0f);
  } else if (r < W2_OFF) {
    int rr = r - W1_OFF;
    int n = rr >> 8, k = rr & 255;
    v = w1[k * HID + n];
  } else {
    int rr = r - W2_OFF;
    int n = rr >> 8, k = rr & 255;
    int od = (m == 0) ? 8 : 24;
    v = (n < od) ? w2[k * od + n] : 0.0f;
  }
  ws[idx] = (__bf16)v;
}

__device__ __forceinline__ float lrelu(float v) { return v > 0.f ? v : 0.01f * v; }

__device__ __forceinline__ void gload16(const void* g, void* l) {
  __builtin_amdgcn_global_load_lds(
      (const __attribute__((address_space(1))) void*)g,
      (__attribute__((address_space(3))) void*)l, 16, 0, 0);
}

// stage one 32-col chunk (16KB) with 512 threads (2 rounds x 8KB = 2 vmem/thread);
// source pre-swizzled so LDS byte a holds W[col=a>>9][k_byte=(a&511)^((col&31)<<4)]
__device__ __forceinline__ void stage(const __bf16* __restrict__ wsrc, __bf16* buf, int tid) {
  #pragma unroll
  for (int r = 0; r < 2; ++r) {
    const int a  = (r * NTHR + tid) * 16;
    const int lc = a >> 9;
    const int un = (a & 511) ^ ((lc & 31) << 4);
    gload16(wsrc + lc * 256 + (un >> 1), (char*)buf + r * (NTHR * 16) + (tid >> 6) * 1024);
  }
}

// Dual-path pair gemm: even chunk A-frags from LDS (swizzled ds_read_b128),
// odd chunk A-frags direct from global (linear, L1-cached; 16KB chunk shared by
// all 8 barrier-synced waves). LDS pipe and vmem/L1 pipe run concurrently.
template<int NKK>
__device__ __forceinline__ void gemm_mix(const __bf16* lbuf, const __bf16* __restrict__ gsrc,
                                         const bf16x8* bfr, f32x16& accL, f32x16& accG,
                                         int r32, int h) {
  const int sw = r32 << 4;
  const char* abase = (const char*)lbuf + (r32 << 9);
  const char* gbase = (const char*)gsrc + (r32 << 9);
  #pragma unroll
  for (int kk = 0; kk < NKK; ++kk) {
    const int off = (kk << 5) + (h << 4);
    bf16x8 aL = *(const bf16x8*)(abase + (off ^ sw));
    bf16x8 aG = *(const bf16x8*)(gbase + off);
    accL = __builtin_amdgcn_mfma_f32_32x32x16_bf16(aL, bfr[kk], accL, 0, 0, 0);
    accG = __builtin_amdgcn_mfma_f32_32x32x16_bf16(aG, bfr[kk], accG, 0, 0, 0);
  }
}

__device__ __forceinline__ bf16x4 shfl32(bf16x4 x) {
  union { bf16x4 v; unsigned long long u; } t;
  t.v = x;
  t.u = __shfl_xor(t.u, 32, 64);
  return t.v;
}
__device__ __forceinline__ bf16x8 cat44(bf16x4 lo, bf16x4 hi) {
  return (bf16x8){lo[0], lo[1], lo[2], lo[3], hi[0], hi[1], hi[2], hi[3]};
}

struct Frag2 { bf16x8 f0, f1; };

// One 32-col D block -> 2 next-layer B-frags (k = 32c..+16, 32c+16..+32).
// D layout (verified): n = lane&31, m = (reg&3) + 8*(reg>>2) + 4*h. Lane-half h owns
// quads {2t+h}; one shfl_xor(32) per 2 quads completes each frag.
template<bool BIAS, bool LR>
__device__ __forceinline__ Frag2 d2frags(const f32x16 acc, const float* bias, int h) {
  bf16x4 pk[4];
  #pragma unroll
  for (int t = 0; t < 4; ++t) {
    float bx = 0.f, by = 0.f, bz = 0.f, bw = 0.f;
    if (BIAS) {
      float4 bv = *(const float4*)(bias + 8 * t + 4 * h);
      bx = bv.x; by = bv.y; bz = bv.z; bw = bv.w;
    }
    float v0 = acc[4 * t] + bx, v1 = acc[4 * t + 1] + by;
    float v2 = acc[4 * t + 2] + bz, v3 = acc[4 * t + 3] + bw;
    if (LR) { v0 = lrelu(v0); v1 = lrelu(v1); v2 = lrelu(v2); v3 = lrelu(v3); }
    pk[t] = (bf16x4){(__bf16)v0, (__bf16)v1, (__bf16)v2, (__bf16)v3};
  }
  bf16x4 r1 = shfl32(h ? pk[0] : pk[1]);
  bf16x4 r2 = shfl32(h ? pk[2] : pk[3]);
  Frag2 out;
  out.f0 = h ? cat44(r1, pk[1]) : cat44(pk[0], r1);
  out.f1 = h ? cat44(r2, pk[3]) : cat44(pk[2], r2);
  return out;
}

__device__ __forceinline__ bf16x8 packf44(float4 a, float4 b) {
  return (bf16x8){(__bf16)a.x, (__bf16)a.y, (__bf16)a.z, (__bf16)a.w,
                  (__bf16)b.x, (__bf16)b.y, (__bf16)b.z, (__bf16)b.w};
}
__device__ __forceinline__ bf16x8 packf2222(float2 a, float2 b, float2 c, float2 d) {
  return (bf16x8){(__bf16)a.x, (__bf16)a.y, (__bf16)b.x, (__bf16)b.y,
                  (__bf16)c.x, (__bf16)c.y, (__bf16)d.x, (__bf16)d.y};
}

__global__ __launch_bounds__(NTHR, 2) void trunk_fused(
    const float* __restrict__ sparse, const float* __restrict__ dec,
    const __bf16* __restrict__ ws, float* __restrict__ out, Biases bp)
{
  __shared__ __align__(16) __bf16 lds[2 * CSZ];  // 32KB: 2 x 16KB banks (even chunks only)
  __bf16* const buf0 = lds;
  __bf16* const buf1 = lds + CSZ;

  const int tid  = threadIdx.x;
  const int lane = tid & 63;
  const int wid  = tid >> 6;
  const int r32  = lane & 31;     // x-row within wave / W-col within 32-chunk
  const int h    = lane >> 5;     // k sub-half
  const long grow = (long)blockIdx.x * BM + wid * RPW + r32;

  // issue first stage (MLP0 W0 even chunk 0) before the gather, hide latency
  stage(ws, buf0, tid);

  // ---- gather x B-frags: xb[kf] = x[row=r32][k = 16kf + 8h .. +8]; chunk cc = 2kf+h
  // node order [0,3,6,9,12,13,14,15,16,17,18,19,20,21] + parent chain 21..0
  bf16x8 xb[14];
  {
    constexpr int ND[21] = {0,3,6,9,12,13,14,15,16,17,18,19,20,21,19,17,14,9,6,3,0};
    const float* drow = dec + grow * DDEC;
    const float* srow = sparse + grow * DSP;
    #pragma unroll
    for (int kf = 0; kf < 14; ++kf) {
      if (kf <= 9) {
        const int off = (h ? ND[2 * kf + 1] : ND[2 * kf]) * 8;
        const float4* p = (const float4*)(drow + off);
        xb[kf] = packf44(p[0], p[1]);
      } else if (kf == 10) {
        if (h == 0) {
          const float4* p = (const float4*)(drow + ND[20] * 8);
          xb[kf] = packf44(p[0], p[1]);
        } else {
          const float2* q = (const float2*)(srow + 0);
          xb[kf] = packf2222(q[0], q[1], q[2], q[3]);
        }
      } else if (kf <= 12) {
        const float2* q = (const float2*)(srow + (2 * kf + h - 21) * 8);
        xb[kf] = packf2222(q[0], q[1], q[2], q[3]);
      } else {
        if (h == 0) {
          const float2* q = (const float2*)(srow + 40);
          xb[kf] = packf2222(q[0], q[1], q[2], q[3]);
        } else {
          const float2* q = (const float2*)(srow + 48);
          xb[kf] = packf2222(q[0], q[1], q[2], make_float2(1.0f, 0.0f));  // k222 = b0 hook
        }
      }
    }
  }
  __syncthreads();
  int pb = 0;

  #pragma unroll
  for (int m = 0; m < 3; ++m) {
    const __bf16* W0 = ws + m * MLP_WS;
    const __bf16* W1 = W0 + W1_OFF;
    const __bf16* W2 = W0 + W2_OFF;
    const float* b1 = bp.b1[m];
    const float* b2 = bp.b2[m];

    bf16x8 hb1[16];
    f32x16 a2 = {};   // layer-2 accumulator, filled across the 4 layer-1 pairs

    // ---- layer 0: 4 pairs; even chunk (cols 64p..+31) via LDS, odd (64p+32..+63)
    // via global/L1. K=224 (14 k-steps), bias folded at k=222.
    #pragma unroll
    for (int p = 0; p < 4; ++p) {
      __bf16* cur = pb ? buf1 : buf0;
      __bf16* nxt = pb ? buf0 : buf1;
      stage(p < 3 ? W0 + (2 * p + 2) * CSZ : W1, nxt, tid);   // next even chunk
      f32x16 accL = {}, accG = {};
      gemm_mix<14>(cur, W0 + (2 * p + 1) * CSZ, xb, accL, accG, r32, h);
      Frag2 tL = d2frags<false, true>(accL, nullptr, h);
      Frag2 tG = d2frags<false, true>(accG, nullptr, h);
      hb1[4 * p]     = tL.f0;  hb1[4 * p + 1] = tL.f1;
      hb1[4 * p + 2] = tG.f0;  hb1[4 * p + 3] = tG.f1;
      __syncthreads();
      pb ^= 1;
    }

    // ---- layer 1: 4 pairs (K=256), layer 2 folded in per pair.
    // W2 A-frags (16KB, L2-hot) also direct from global.
    #pragma unroll
    for (int p = 0; p < 4; ++p) {
      __bf16* cur = pb ? buf1 : buf0;
      __bf16* nxt = pb ? buf0 : buf1;
      if (p < 3)      stage(W1 + (2 * p + 2) * CSZ, nxt, tid);
      else if (m < 2) stage(ws + (m + 1) * MLP_WS, nxt, tid);
      const __bf16* w2f = W2 + r32 * 256 + h * 8 + 64 * p;
      bf16x8 wa0 = *(const bf16x8*)(w2f + 0);
      bf16x8 wa1 = *(const bf16x8*)(w2f + 16);
      bf16x8 wa2 = *(const bf16x8*)(w2f + 32);
      bf16x8 wa3 = *(const bf16x8*)(w2f + 48);
      f32x16 accL = {}, accG = {};
      gemm_mix<16>(cur, W1 + (2 * p + 1) * CSZ, hb1, accL, accG, r32, h);
      Frag2 tL = d2frags<true, true>(accL, b1 + 64 * p, h);
      Frag2 tG = d2frags<true, true>(accG, b1 + 64 * p + 32, h);
      a2 = __builtin_amdgcn_mfma_f32_32x32x16_bf16(wa0, tL.f0, a2, 0, 0, 0);
      a2 = __builtin_amdgcn_mfma_f32_32x32x16_bf16(wa1, tL.f1, a2, 0, 0, 0);
      a2 = __builtin_amdgcn_mfma_f32_32x32x16_bf16(wa2, tG.f0, a2, 0, 0, 0);
      a2 = __builtin_amdgcn_mfma_f32_32x32x16_bf16(wa3, tG.f1, a2, 0, 0, 0);
      __syncthreads();
      pb ^= 1;
    }

    // ---- epilogue: a2 = out^T frag (lane r32 = its own x-row; quads 2t+h -> cols 8t+4h..+3)
    if (m == 2) {
      #pragma unroll
      for (int t = 0; t < 3; ++t) {
        const int c0 = 8 * t + 4 * h;
        float4 bv = *(const float4*)(b2 + c0);
        float4 o;
        o.x = a2[4 * t]     + bv.x;
        o.y = a2[4 * t + 1] + bv.y;
        o.z = a2[4 * t + 2] + bv.z;
        o.w = a2[4 * t + 3] + bv.w;
        *(float4*)(out + grow * 24 + c0) = o;
      }
    } else {
      bf16x4 pk[3];
      #pragma unroll
      for (int t = 0; t < 3; ++t) {
        const int c0 = 8 * t + 4 * h;
        float4 bv = *(const float4*)(b2 + c0);
        pk[t] = (bf16x4){(__bf16)(a2[4 * t] + bv.x),     (__bf16)(a2[4 * t + 1] + bv.y),
                         (__bf16)(a2[4 * t + 2] + bv.z), (__bf16)(a2[4 * t + 3] + bv.w)};
      }
      if (m == 0) {
        // res1 = joint 9 (cols 0-7) -> chunks 3 (xb[1],h1) and 17 (xb[8],h1)
        bf16x4 r = shfl32(pk[0]);
        if (h) { bf16x8 f = cat44(r, pk[0]); xb[1] = f; xb[8] = f; }
      } else {
        // res2: joint6 (0-7)->chunks 2,18 (h0); joint9 (8-15)->3,17 (h1); joint12 (16-23)->4 (h0)
        bf16x4 r1 = shfl32(h ? pk[0] : pk[1]);
        bf16x4 r2 = shfl32(pk[2]);
        if (h) {
          bf16x8 fJ9 = cat44(r1, pk[1]);  xb[1] = fJ9;  xb[8] = fJ9;
        } else {
          bf16x8 fJ6  = cat44(pk[0], r1); xb[1] = fJ6;  xb[9] = fJ6;
          bf16x8 fJ12 = cat44(pk[2], r2); xb[2] = fJ12;
        }
      }
    }
  }
}

extern "C" void kernel_launch(void* const* d_in, const int* in_sizes, int n_in,
                              void* d_out, int out_size, void* d_ws, size_t ws_size,
                              hipStream_t stream)
{
  const float* sparse = (const float*)d_in[0];
  const float* dec    = (const float*)d_in[1];
  Biases bp;
  const float* w0[3]; const float* w1[3]; const float* w2[3]; const float* b0[3];
  for (int m = 0; m < 3; ++m) {
    w0[m]    = (const float*)d_in[2 + m * 6 + 0];
    b0[m]    = (const float*)d_in[2 + m * 6 + 1];
    w1[m]    = (const float*)d_in[2 + m * 6 + 2];
    bp.b1[m] = (const float*)d_in[2 + m * 6 + 3];
    w2[m]    = (const float*)d_in[2 + m * 6 + 4];
    bp.b2[m] = (const float*)d_in[2 + m * 6 + 5];
  }
  __bf16* ws = (__bf16*)d_ws;
  const int nrows = in_sizes[0] / DSP;   // 131072 = 512 * 256

  const int prep_total = 3 * MLP_WS;
  prep_weights<<<(prep_total + 255) / 256, 256, 0, stream>>>(
      w0[0], w1[0], w2[0], w0[1], w1[1], w2[1], w0[2], w1[2], w2[2],
      b0[0], b0[1], b0[2], ws);

  const int nblocks = nrows / BM;
  trunk_fused<<<nblocks, NTHR, 0, stream>>>(sparse, dec, ws, (float*)d_out, bp);
}

// Round 18
// 188.067 us; speedup vs baseline: 1.4111x; 1.4111x over previous
//
#include <hip/hip_runtime.h>

typedef __bf16 bf16x8 __attribute__((ext_vector_type(8)));
typedef __bf16 bf16x4 __attribute__((ext_vector_type(4)));
typedef float  f32x4v __attribute__((ext_vector_type(4)));
typedef float  f32x16 __attribute__((ext_vector_type(16)));

#define DDEC  176
#define DSP   54
#define RT    32             // rows per tile (all 8 waves cooperate)
#define NTILE 16             // tiles per block
#define BROWS (RT * NTILE)   // 512 rows per block
#define NTHR  512
#define W1_OFF 65536
#define W2_OFF 131072
#define MLP_WS 139264

__constant__ int c_nd[21] = {0,3,6,9,12,13,14,15,16,17,18,19,20,21,19,17,14,9,6,3,0};

struct Biases { const float* b1[3]; const float* b2[3]; };

// ---- prep: pad/transpose weights to bf16 [col][256 k] per layer
// W0p[256][256] (k<222 = w0[k][n], k==222 = b0[n], else 0), W1p[256][256], W2p[32][256]
__global__ __launch_bounds__(256) void prep_weights(
    const float* __restrict__ w0a, const float* __restrict__ w1a, const float* __restrict__ w2a,
    const float* __restrict__ w0b, const float* __restrict__ w1b, const float* __restrict__ w2b,
    const float* __restrict__ w0c, const float* __restrict__ w1c, const float* __restrict__ w2c,
    const float* __restrict__ b0a, const float* __restrict__ b0b, const float* __restrict__ b0c,
    __bf16* __restrict__ ws)
{
  int idx = blockIdx.x * 256 + threadIdx.x;
  if (idx >= 3 * MLP_WS) return;
  int m = idx / MLP_WS;
  int r = idx - m * MLP_WS;
  const float* w0 = (m == 0) ? w0a : (m == 1) ? w0b : w0c;
  const float* w1 = (m == 0) ? w1a : (m == 1) ? w1b : w1c;
  const float* w2 = (m == 0) ? w2a : (m == 1) ? w2b : w2c;
  const float* b0 = (m == 0) ? b0a : (m == 1) ? b0b : b0c;
  float v;
  if (r < W1_OFF) {
    int n = r >> 8, k = r & 255;
    v = (k < 222) ? w0[k * 256 + n] : (k == 222 ? b0[n] : 0.0f);
  } else if (r < W2_OFF) {
    int rr = r - W1_OFF;
    int n = rr >> 8, k = rr & 255;
    v = w1[k * 256 + n];
  } else {
    int rr = r - W2_OFF;
    int n = rr >> 8, k = rr & 255;
    int od = (m == 0) ? 8 : 24;
    v = (n < od) ? w2[k * od + n] : 0.0f;
  }
  ws[idx] = (__bf16)v;
}

__device__ __forceinline__ float lrelu(float v) { return v > 0.f ? v : 0.01f * v; }

__device__ __forceinline__ bf16x4 shfl32(bf16x4 x) {
  union { bf16x4 v; unsigned long long u; } t;
  t.v = x;
  t.u = __shfl_xor(t.u, 32, 64);
  return t.v;
}
__device__ __forceinline__ bf16x8 cat44(bf16x4 lo, bf16x4 hi) {
  return (bf16x8){lo[0], lo[1], lo[2], lo[3], hi[0], hi[1], hi[2], hi[3]};
}
__device__ __forceinline__ bf16x8 packf44(float4 a, float4 b) {
  return (bf16x8){(__bf16)a.x, (__bf16)a.y, (__bf16)a.z, (__bf16)a.w,
                  (__bf16)b.x, (__bf16)b.y, (__bf16)b.z, (__bf16)b.w};
}

struct Frag2 { bf16x8 f0, f1; };

// One 32-col D block -> 2 next-layer B-frags (verified r6-r17).
// D: x-row = lane&31, h-col-offset = (reg&3)+8*(reg>>2)+4*h.
template<bool BIAS, bool LR>
__device__ __forceinline__ Frag2 d2frags(const f32x16 acc, const float* bias, int h) {
  bf16x4 pk[4];
  #pragma unroll
  for (int t = 0; t < 4; ++t) {
    float bx = 0.f, by = 0.f, bz = 0.f, bw = 0.f;
    if (BIAS) {
      float4 bv = *(const float4*)(bias + 8 * t + 4 * h);
      bx = bv.x; by = bv.y; bz = bv.z; bw = bv.w;
    }
    float v0 = acc[4 * t] + bx, v1 = acc[4 * t + 1] + by;
    float v2 = acc[4 * t + 2] + bz, v3 = acc[4 * t + 3] + bw;
    if (LR) { v0 = lrelu(v0); v1 = lrelu(v1); v2 = lrelu(v2); v3 = lrelu(v3); }
    pk[t] = (bf16x4){(__bf16)v0, (__bf16)v1, (__bf16)v2, (__bf16)v3};
  }
  bf16x4 r1 = shfl32(h ? pk[0] : pk[1]);
  bf16x4 r2 = shfl32(h ? pk[2] : pk[3]);
  Frag2 out;
  out.f0 = h ? cat44(r1, pk[1]) : cat44(pk[0], r1);
  out.f1 = h ? cat44(r2, pk[3]) : cat44(pk[2], r2);
  return out;
}

struct GR { float4 a, b; };

// raw x granule g (8 floats) for one row
__device__ __forceinline__ GR load_gran(const float* __restrict__ drow,
                                        const float* __restrict__ srow, int g, int nd) {
  GR o;
  if (g < 21) {
    const float4* p = (const float4*)(drow + nd * 8);
    o.a = p[0]; o.b = p[1];
  } else if (g < 27) {
    const float2* q = (const float2*)(srow + 8 * (g - 21));
    o.a = make_float4(q[0].x, q[0].y, q[1].x, q[1].y);
    o.b = make_float4(q[2].x, q[2].y, q[3].x, q[3].y);
  } else if (g == 27) {
    const float2* q = (const float2*)(srow + 48);
    o.a = make_float4(q[0].x, q[0].y, q[1].x, q[1].y);
    o.b = make_float4(q[2].x, q[2].y, 1.0f, 0.0f);   // k222 = b0 hook, k223 = 0
  } else {
    o.a = make_float4(0.f, 0.f, 0.f, 0.f); o.b = o.a;
  }
  return o;
}

// write granule g of row r into swizzled xbuf; patched granules come from resrow
__device__ __forceinline__ void write_gran(__bf16* xb, const __bf16* resrow,
                                           int r, int g, int mp, GR v) {
  int src = -1;
  if (mp == 1)      { if (g == 3 || g == 17) src = 0; }
  else if (mp == 2) { if (g == 2 || g == 18) src = 0;
                      else if (g == 3 || g == 17) src = 8;
                      else if (g == 4) src = 16; }
  bf16x8 val = (src >= 0) ? *(const bf16x8*)(resrow + src) : packf44(v.a, v.b);
  *(bf16x8*)(xb + r * 256 + ((g ^ r) & 31) * 8) = val;
}

// Weights-in-registers fused trunk. 8 waves x 32 weight-cols; block does 512 rows
// as 16 tiles of 32; m outer (weights reloaded 3x); activations through LDS.
__global__ __launch_bounds__(NTHR, 2) void trunk_fused(
    const float* __restrict__ sparse, const float* __restrict__ dec,
    const __bf16* __restrict__ ws, float* __restrict__ out, Biases bp)
{
  __shared__ __align__(16) __bf16 xbuf[2 * 8192];   // 2 x 16KB swizzled x tiles
  __shared__ __align__(16) __bf16 hbuf[8192];       // 16KB swizzled h tile
  __shared__ __align__(16) float  rbuf[8 * 1024];   // 32KB: 8 partial a2 slots
  __shared__ __align__(16) __bf16 resb[BROWS * 32]; // 32KB: per-row res (bias applied)

  const int tid  = threadIdx.x;
  const int lane = tid & 63;
  const int wid  = tid >> 6;       // wave = its 32 weight-cols
  const int r32  = lane & 31;      // x-row within tile / out-col for W2 A-frag
  const int h    = lane >> 5;
  const long row0 = (long)blockIdx.x * BROWS;

  // per-thread gather constants: row gr, granules g0,g1
  const int gr = tid >> 4;
  const int g0 = (tid & 15) * 2;
  const int g1 = g0 + 1;
  const int nd0 = (g0 < 21) ? c_nd[g0] : 0;
  const int nd1 = (g1 < 21) ? c_nd[g1] : 0;

  // prologue: gather tile 0 (no patch)
  {
    const float* drow = dec + (row0 + gr) * DDEC;
    const float* srow = sparse + (row0 + gr) * DSP;
    GR v0 = load_gran(drow, srow, g0, nd0);
    GR v1 = load_gran(drow, srow, g1, nd1);
    write_gran(xbuf, resb, gr, g0, 0, v0);
    write_gran(xbuf, resb, gr, g1, 0, v1);
  }
  __syncthreads();

  for (int m = 0; m < 3; ++m) {
    const __bf16* W0 = ws + m * MLP_WS;
    const __bf16* W1 = W0 + W1_OFF;
    const __bf16* W2 = W0 + W2_OFF;
    const float* b1 = bp.b1[m];
    const float* b2 = bp.b2[m];

    // ---- load wave's weight slices into registers (L2-hot, once per m)
    bf16x8 w0r[14], w1r[16], w2r[2];
    {
      const __bf16* p0 = W0 + (size_t)(32 * wid + r32) * 256 + 8 * h;
      #pragma unroll
      for (int kk = 0; kk < 14; ++kk) w0r[kk] = *(const bf16x8*)(p0 + 16 * kk);
      const __bf16* p1 = W1 + (size_t)(32 * wid + r32) * 256 + 8 * h;
      #pragma unroll
      for (int kk = 0; kk < 16; ++kk) w1r[kk] = *(const bf16x8*)(p1 + 16 * kk);
      const __bf16* p2 = W2 + (size_t)r32 * 256 + 32 * wid + 8 * h;
      w2r[0] = *(const bf16x8*)(p2);
      w2r[1] = *(const bf16x8*)(p2 + 16);
    }

    for (int t = 0; t < NTILE; ++t) {
      const int p = t & 1;
      const __bf16* xcur = xbuf + p * 8192;

      // ---- L0: pure-register A (w0r), B-frags from swizzled xbuf
      f32x16 acc = {};
      {
        const __bf16* xrow = xcur + r32 * 256;
        #pragma unroll
        for (int kk = 0; kk < 14; ++kk) {
          bf16x8 bfr = *(const bf16x8*)(xrow + (((2 * kk + h) ^ r32) & 31) * 8);
          acc = __builtin_amdgcn_mfma_f32_32x32x16_bf16(w0r[kk], bfr, acc, 0, 0, 0);
        }
      }
      Frag2 th1 = d2frags<false, true>(acc, nullptr, h);
      {
        __bf16* hrow = hbuf + r32 * 256;
        *(bf16x8*)(hrow + (((4 * wid + h) ^ r32) & 31) * 8)     = th1.f0;
        *(bf16x8*)(hrow + (((4 * wid + 2 + h) ^ r32) & 31) * 8) = th1.f1;
      }
      __syncthreads();

      // ---- prefetch next tile's x (issue early; cvt+write late in D)
      const int gphase = m * NTILE + t;
      const bool dopf = (gphase + 1 < 3 * NTILE);
      GR v0, v1;
      if (dopf) {
        const long nrow = row0 + ((t + 1 < NTILE) ? (t + 1) * RT : 0) + gr;
        const float* drow = dec + nrow * DDEC;
        const float* srow = sparse + nrow * DSP;
        v0 = load_gran(drow, srow, g0, nd0);
        v1 = load_gran(drow, srow, g1, nd1);
      }

      // ---- L1: A = w1r, B-frags from hbuf
      f32x16 acc1 = {};
      {
        const __bf16* hrow = hbuf + r32 * 256;
        #pragma unroll
        for (int kk = 0; kk < 16; ++kk) {
          bf16x8 bfr = *(const bf16x8*)(hrow + (((2 * kk + h) ^ r32) & 31) * 8);
          acc1 = __builtin_amdgcn_mfma_f32_32x32x16_bf16(w1r[kk], bfr, acc1, 0, 0, 0);
        }
      }
      Frag2 th2 = d2frags<true, true>(acc1, b1 + 32 * wid, h);

      // ---- L2 partial: wave's own k-slice (h2 frags still in regs)
      f32x16 a2 = {};
      a2 = __builtin_amdgcn_mfma_f32_32x32x16_bf16(w2r[0], th2.f0, a2, 0, 0, 0);
      a2 = __builtin_amdgcn_mfma_f32_32x32x16_bf16(w2r[1], th2.f1, a2, 0, 0, 0);
      {
        // a2: lane r32 = x-row; quads = out-col groups. store [w][row][colswz]
        float* rb = rbuf + wid * 1024 + r32 * 32;
        #pragma unroll
        for (int q = 0; q < 4; ++q) {
          f32x4v val = {a2[4 * q], a2[4 * q + 1], a2[4 * q + 2], a2[4 * q + 3]};
          *(f32x4v*)(rb + 4 * (((2 * q + h) ^ (r32 & 7)) & 7)) = val;
        }
      }
      __syncthreads();

      // ---- reduce 8 partials + bias; emit out (m==2) or res (m<2); write next x
      for (int i = tid; i < 768; i += NTHR) {
        const int c = i % 24;
        const int r = i / 24;
        const int ro = r * 32 + 4 * (((c >> 2) ^ (r & 7)) & 7) + (c & 3);
        float s = 0.f;
        #pragma unroll
        for (int w = 0; w < 8; ++w) s += rbuf[w * 1024 + ro];
        s += b2[c];
        if (m == 2) out[(row0 + t * RT + r) * 24 + c] = s;
        else        resb[(t * RT + r) * 32 + c] = (__bf16)s;
      }
      if (dopf) {
        const int mp = (t + 1 < NTILE) ? m : m + 1;
        const int tn = (t + 1 < NTILE) ? t + 1 : 0;
        __bf16* xnxt = xbuf + (p ^ 1) * 8192;
        const __bf16* resrow = resb + (tn * RT + gr) * 32;
        write_gran(xnxt, resrow, gr, g0, mp, v0);
        write_gran(xnxt, resrow, gr, g1, mp, v1);
      }
      __syncthreads();
    }
  }
}

extern "C" void kernel_launch(void* const* d_in, const int* in_sizes, int n_in,
                              void* d_out, int out_size, void* d_ws, size_t ws_size,
                              hipStream_t stream)
{
  const float* sparse = (const float*)d_in[0];
  const float* dec    = (const float*)d_in[1];
  Biases bp;
  const float* w0[3]; const float* w1[3]; const float* w2[3]; const float* b0[3];
  for (int m = 0; m < 3; ++m) {
    w0[m]    = (const float*)d_in[2 + m * 6 + 0];
    b0[m]    = (const float*)d_in[2 + m * 6 + 1];
    w1[m]    = (const float*)d_in[2 + m * 6 + 2];
    bp.b1[m] = (const float*)d_in[2 + m * 6 + 3];
    w2[m]    = (const float*)d_in[2 + m * 6 + 4];
    bp.b2[m] = (const float*)d_in[2 + m * 6 + 5];
  }
  __bf16* ws = (__bf16*)d_ws;
  const int nrows = in_sizes[0] / DSP;   // 131072 = 256 * 512

  const int prep_total = 3 * MLP_WS;
  prep_weights<<<(prep_total + 255) / 256, 256, 0, stream>>>(
      w0[0], w1[0], w2[0], w0[1], w1[1], w2[1], w0[2], w1[2], w2[2],
      b0[0], b0[1], b0[2], ws);

  const int nblocks = nrows / BROWS;   // 256 blocks = 1 per CU
  trunk_fused<<<nblocks, NTHR, 0, stream>>>(sparse, dec, ws, (float*)d_out, bp);
}